// Round 1
// baseline (54.583 us; speedup 1.0000x reference)
//
#include <hip/hip_runtime.h>

#define NB 4
#define NS 1024
#define NE 128
#define NH 16
#define ND 8

// ---------------------------------------------------------------------------
// Kernel 1: fused quantum-layer + per-head self-attention.
// Math: proj[0] = prod_{j=1..7} cos(x_j+phi_j); proj[w] = prod_{j=0..w} cos(x_j+phi_j)
// (the CNOT chain only permutes basis states; probabilities stay a classical
//  product distribution, so exps reduce to products of cos(x+phi)).
// Scores are bounded by sqrt(8) => softmax needs no max subtraction.
// grid = (B*H)*8 blocks; block = 512 threads = 128 queries x 4 key-chunks.
// Output written in (B,S,E) layout directly into d_out.
// ---------------------------------------------------------------------------
__global__ __launch_bounds__(512)
void qattn_kernel(const float* __restrict__ x, const float* __restrict__ phi,
                  float* __restrict__ aout)
{
    __shared__ float4 Ks[NS * 2];      // 32 KB: K/V rows (8 f32 each) for this head
    __shared__ float  red[512 * 9];    // 18 KB: partial (acc[8], l) per thread

    const int t    = threadIdx.x;
    const int blk  = blockIdx.x;
    const int tile = blk & 7;          // query tile (128 queries)
    const int bh   = blk >> 3;
    const int b    = bh >> 4;
    const int h    = bh & 15;

    float ph[ND];
#pragma unroll
    for (int j = 0; j < ND; ++j) ph[j] = phi[j];

    // ---- stage K: compute quantum layer on the fly ----
    const float* xb = x + ((size_t)b * NS) * NE + h * ND;
    for (int s = t; s < NS; s += 512) {
        const float* xr = xb + (size_t)s * NE;
        float4 xa = *(const float4*)(xr);
        float4 xc = *(const float4*)(xr + 4);
        float g0 = __cosf(xa.x + ph[0]);
        float g1 = __cosf(xa.y + ph[1]);
        float g2 = __cosf(xa.z + ph[2]);
        float g3 = __cosf(xa.w + ph[3]);
        float g4 = __cosf(xc.x + ph[4]);
        float g5 = __cosf(xc.y + ph[5]);
        float g6 = __cosf(xc.z + ph[6]);
        float g7 = __cosf(xc.w + ph[7]);
        float p1 = g0 * g1;
        float p2 = p1 * g2;
        float p3 = p2 * g3;
        float p4 = p3 * g4;
        float p5 = p4 * g5;
        float p6 = p5 * g6;
        float p7 = p6 * g7;
        float s7 = g7;
        float s6 = s7 * g6;
        float s5 = s6 * g5;
        float s4 = s5 * g4;
        float s3 = s4 * g3;
        float s2 = s3 * g2;
        float s1 = s2 * g1;            // g1*...*g7  (wire 0 expectation)
        Ks[2 * s]     = make_float4(s1, p1, p2, p3);
        Ks[2 * s + 1] = make_float4(p4, p5, p6, p7);
    }
    __syncthreads();

    // ---- attention: each thread = one query row over one 256-key chunk ----
    const int q     = t & 127;
    const int chunk = t >> 7;
    const int qs    = tile * 128 + q;

    const float SC = 0.35355339059327373f;   // 1/sqrt(8)
    float4 qa = Ks[2 * qs], qb = Ks[2 * qs + 1];
    qa.x *= SC; qa.y *= SC; qa.z *= SC; qa.w *= SC;
    qb.x *= SC; qb.y *= SC; qb.z *= SC; qb.w *= SC;

    float l = 0.0f;
    float a0 = 0, a1 = 0, a2 = 0, a3 = 0, a4 = 0, a5 = 0, a6 = 0, a7 = 0;
    const int j0 = chunk * 256;
#pragma unroll 4
    for (int j = j0; j < j0 + 256; ++j) {
        float4 ka = Ks[2 * j], kb = Ks[2 * j + 1];   // broadcast LDS reads
        float s = qa.x * ka.x + qa.y * ka.y + qa.z * ka.z + qa.w * ka.w
                + qb.x * kb.x + qb.y * kb.y + qb.z * kb.z + qb.w * kb.w;
        float p = __expf(s);                          // bounded: |s| <= 2.83
        l  += p;
        a0 += p * ka.x; a1 += p * ka.y; a2 += p * ka.z; a3 += p * ka.w;
        a4 += p * kb.x; a5 += p * kb.y; a6 += p * kb.z; a7 += p * kb.w;
    }

    // ---- combine the 4 key-chunk partials (exact: no max tracking) ----
    float* rp = red + t * 9;
    rp[0] = a0; rp[1] = a1; rp[2] = a2; rp[3] = a3;
    rp[4] = a4; rp[5] = a5; rp[6] = a6; rp[7] = a7; rp[8] = l;
    __syncthreads();
    if (t < 256) {
        float* a = red + t * 9;
        const float* c = red + (t + 256) * 9;
#pragma unroll
        for (int e = 0; e < 9; ++e) a[e] += c[e];
    }
    __syncthreads();
    if (t < 128) {
        const float* a = red + t * 9;
        const float* c = red + (t + 128) * 9;
        float inv = 1.0f / (a[8] + c[8]);
        float o0 = (a[0] + c[0]) * inv, o1 = (a[1] + c[1]) * inv;
        float o2 = (a[2] + c[2]) * inv, o3 = (a[3] + c[3]) * inv;
        float o4 = (a[4] + c[4]) * inv, o5 = (a[5] + c[5]) * inv;
        float o6 = (a[6] + c[6]) * inv, o7 = (a[7] + c[7]) * inv;
        float* op = aout + ((size_t)b * NS + (size_t)(tile * 128 + t)) * NE + h * ND;
        *(float4*)op       = make_float4(o0, o1, o2, o3);
        *(float4*)(op + 4) = make_float4(o4, o5, o6, o7);
    }
}

// ---------------------------------------------------------------------------
// Kernel 2: out = A @ W^T + b, A = (4096,128) attention output (in d_out),
// computed in place (each block reads only the 16 rows it writes).
// W staged transposed into LDS in two 64-wide e-halves (static LDS <= 64KB).
// ---------------------------------------------------------------------------
__global__ __launch_bounds__(256)
void proj_kernel(const float* __restrict__ A, const float* __restrict__ W,
                 const float* __restrict__ bias, float* __restrict__ out)
{
    __shared__ float Wt[64][NE + 4];   // 33.8 KB, transposed half of W, padded
    __shared__ float As[16][NE];       // 8 KB

    const int t  = threadIdx.x;
    const int r0 = blockIdx.x * 16;

    for (int i = t; i < 16 * NE; i += 256) {
        As[i >> 7][i & 127] = A[(size_t)(r0 + (i >> 7)) * NE + (i & 127)];
    }

    const int c4 = (t & 31) * 4;
    const int rg = t >> 5;                     // rows rg*2, rg*2+1
    float acc00 = 0, acc01 = 0, acc02 = 0, acc03 = 0;
    float acc10 = 0, acc11 = 0, acc12 = 0, acc13 = 0;

    for (int eh = 0; eh < 2; ++eh) {
        if (eh) __syncthreads();               // previous half fully consumed
        for (int i = t; i < NE * 64; i += 256) {
            int c = i >> 6;
            int e = i & 63;
            Wt[e][c] = W[c * NE + eh * 64 + e];
        }
        __syncthreads();
#pragma unroll 8
        for (int e = 0; e < 64; ++e) {
            float4 wv = *(const float4*)&Wt[e][c4];
            float av0 = As[rg * 2][eh * 64 + e];
            float av1 = As[rg * 2 + 1][eh * 64 + e];
            acc00 += av0 * wv.x; acc01 += av0 * wv.y;
            acc02 += av0 * wv.z; acc03 += av0 * wv.w;
            acc10 += av1 * wv.x; acc11 += av1 * wv.y;
            acc12 += av1 * wv.z; acc13 += av1 * wv.w;
        }
    }

    float4 bv = *(const float4*)&bias[c4];
    float4 o0 = make_float4(acc00 + bv.x, acc01 + bv.y, acc02 + bv.z, acc03 + bv.w);
    float4 o1 = make_float4(acc10 + bv.x, acc11 + bv.y, acc12 + bv.z, acc13 + bv.w);
    *(float4*)(out + (size_t)(r0 + rg * 2)     * NE + c4) = o0;
    *(float4*)(out + (size_t)(r0 + rg * 2 + 1) * NE + c4) = o1;
}

extern "C" void kernel_launch(void* const* d_in, const int* in_sizes, int n_in,
                              void* d_out, int out_size, void* d_ws, size_t ws_size,
                              hipStream_t stream)
{
    (void)in_sizes; (void)n_in; (void)out_size; (void)d_ws; (void)ws_size;
    const float* x   = (const float*)d_in[0];
    const float* phi = (const float*)d_in[1];
    const float* W   = (const float*)d_in[2];
    const float* b   = (const float*)d_in[3];
    float* out = (float*)d_out;

    qattn_kernel<<<dim3(NB * NH * 8), dim3(512), 0, stream>>>(x, phi, out);
    proj_kernel<<<dim3(NB * NS / 16), dim3(256), 0, stream>>>(out, W, b, out);
}

// Round 3
// 25.132 us; speedup vs baseline: 2.1719x; 2.1719x over previous
//
#include <hip/hip_runtime.h>

#define NB 4
#define NS 1024
#define NE 128
#define NH 16
#define ND 8

typedef __attribute__((ext_vector_type(4))) _Float16 half4v;
typedef __attribute__((ext_vector_type(8))) _Float16 half8v;
typedef __attribute__((ext_vector_type(2))) _Float16 half2v;
typedef __attribute__((ext_vector_type(4))) float float4v;

#if __has_builtin(__builtin_amdgcn_exp2f)
#define EXP2F(x) __builtin_amdgcn_exp2f(x)
#else
#define EXP2F(x) exp2f(x)
#endif

// sqrt(log2(e)/sqrt(8)): both QK^T operands carry this, so MFMA out = log2e/sqrt(8)*(k.q)
#define SQRT_ALPHA 0.71423656f

// ---------------------------------------------------------------------------
// Fused quantum-layer + self-attention via f16 MFMA.
// proj[0]=g1*...*g7, proj[w]=g0*...*gw with g_j=cos(x_j+phi_j)  (CNOTs only
// permute a product distribution -> closed form; verified in round 1).
// S^T = K.Q^T via mfma 16x16x16: lane holds P[q=l&15][keys (l>>4)*4+r] ->
// exactly the PV A-fragment after exp2+cvt_pkrtz (no LDS bounce for P).
// V staged transposed with a ones-row (col 8 of output = softmax denom).
// grid = 64 heads x 8 q-tiles(128q); block 512 thr = 8 waves x 16 queries.
// ---------------------------------------------------------------------------
__global__ __launch_bounds__(512)
void qattn_kernel(const float* __restrict__ x, const float* __restrict__ phi,
                  float* __restrict__ aout)
{
    __shared__ __align__(16) _Float16 Klds[NS][8];     // 16 KB, scaled by SQRT_ALPHA
    __shared__ __align__(16) _Float16 Vt[16][1036];    // 33.2 KB: rows0-7 raw k, row8 ones, 9-15 zero

    const int t    = threadIdx.x;
    const int blk  = blockIdx.x;
    const int qt   = blk & 7;          // 128-query tile
    const int bh   = blk >> 3;
    const int b    = bh >> 4;
    const int h    = bh & 15;
    const int lane = t & 63;
    const int w    = t >> 6;

    // zero Vt pad rows 9..15 (7*1036 halves = 3626 dwords)
    {
        unsigned int* z = (unsigned int*)&Vt[9][0];
        for (int i = t; i < 7 * 518; i += 512) z[i] = 0u;
    }

    const float ph0 = phi[0], ph1 = phi[1], ph2 = phi[2], ph3 = phi[3];
    const float ph4 = phi[4], ph5 = phi[5], ph6 = phi[6], ph7 = phi[7];

    // ---- stage K (scaled) and V^T (raw + ones row) ----
    for (int k = t; k < NS; k += 512) {
        const float* xr = x + ((size_t)(b * NS + k)) * NE + h * ND;
        float4 xa = *(const float4*)xr;
        float4 xc = *(const float4*)(xr + 4);
        float g0 = __cosf(xa.x + ph0), g1 = __cosf(xa.y + ph1);
        float g2 = __cosf(xa.z + ph2), g3 = __cosf(xa.w + ph3);
        float g4 = __cosf(xc.x + ph4), g5 = __cosf(xc.y + ph5);
        float g6 = __cosf(xc.z + ph6), g7 = __cosf(xc.w + ph7);
        float s7 = g7, s6 = s7 * g6, s5 = s6 * g5, s4 = s5 * g4, s3 = s4 * g3, s2 = s3 * g2;
        float v0 = s2 * g1;                         // wire 0 expectation
        float v1 = g0 * g1, v2 = v1 * g2, v3 = v2 * g3;
        float v4 = v3 * g4, v5 = v4 * g5, v6 = v5 * g6, v7 = v6 * g7;
        half8v row;
        row[0] = (_Float16)(SQRT_ALPHA * v0); row[1] = (_Float16)(SQRT_ALPHA * v1);
        row[2] = (_Float16)(SQRT_ALPHA * v2); row[3] = (_Float16)(SQRT_ALPHA * v3);
        row[4] = (_Float16)(SQRT_ALPHA * v4); row[5] = (_Float16)(SQRT_ALPHA * v5);
        row[6] = (_Float16)(SQRT_ALPHA * v6); row[7] = (_Float16)(SQRT_ALPHA * v7);
        *(half8v*)&Klds[k][0] = row;
        Vt[0][k] = (_Float16)v0; Vt[1][k] = (_Float16)v1;
        Vt[2][k] = (_Float16)v2; Vt[3][k] = (_Float16)v3;
        Vt[4][k] = (_Float16)v4; Vt[5][k] = (_Float16)v5;
        Vt[6][k] = (_Float16)v6; Vt[7][k] = (_Float16)v7;
        Vt[8][k] = (_Float16)1.0f;
    }
    __syncthreads();

    const int e = lane & 15;
    const int g = lane >> 4;

    // Q fragment (B operand of S^T): B[kd][q], kd=(l>>4)*4+j, q=l&15.
    // Lanes >=32 cover kd 8..15 -> zero (kills garbage K products too).
    half4v qf = (half4v)(_Float16)0.0f;
    if (lane < 32) {
        int qrow = qt * 128 + w * 16 + e;
        qf = *(const half4v*)&Klds[qrow][g * 4];
    }

    const _Float16* kp = &Klds[e][(g & 1) * 4];   // A: K[t*16+(l&15)][(l>>4)*4+j]
    const _Float16* vp = &Vt[e][g * 4];           // B_V: V[t*16+(l>>4)*4+j][e=l&15]

    float4v acc  = (float4v)0.0f;
    const float4v zero = (float4v)0.0f;

#pragma unroll 8
    for (int tt = 0; tt < 64; ++tt) {
        half4v kf = *(const half4v*)(kp + tt * 128);   // 16 rows * 8 halves
        half4v vf = *(const half4v*)(vp + tt * 16);
        float4v s = __builtin_amdgcn_mfma_f32_16x16x16f16(kf, qf, zero, 0, 0, 0);
        float p0 = EXP2F(s[0]);
        float p1 = EXP2F(s[1]);
        float p2 = EXP2F(s[2]);
        float p3 = EXP2F(s[3]);
        half2v lo = __builtin_bit_cast(half2v, __builtin_amdgcn_cvt_pkrtz(p0, p1));
        half2v hi = __builtin_bit_cast(half2v, __builtin_amdgcn_cvt_pkrtz(p2, p3));
        half4v pa = __builtin_shufflevector(lo, hi, 0, 1, 2, 3);
        acc = __builtin_amdgcn_mfma_f32_16x16x16f16(pa, vf, acc, 0, 0, 0);
    }

    // ---- normalize by column 8 (softmax denom) and store ----
    const int src = (lane & 48) | 8;
    float o0, o1, o2, o3;
    {
        float d0 = __shfl(acc[0], src, 64);
        float d1 = __shfl(acc[1], src, 64);
        float d2 = __shfl(acc[2], src, 64);
        float d3 = __shfl(acc[3], src, 64);
        o0 = acc[0] / d0; o1 = acc[1] / d1; o2 = acc[2] / d2; o3 = acc[3] / d3;
    }
    if (e < 8) {
        size_t rbase = (size_t)(b * NS + qt * 128 + w * 16 + g * 4);
        float* op = aout + rbase * NE + h * ND + e;
        op[0 * NE] = o0;
        op[1 * NE] = o1;
        op[2 * NE] = o2;
        op[3 * NE] = o3;
    }
}

// ---------------------------------------------------------------------------
// out = A @ W^T + b, in place (block reads only the 8 rows it writes).
// 512 blocks x 256 thr (2 waves/SIMD). W transposed-staged in two 64-col halves.
// ---------------------------------------------------------------------------
__global__ __launch_bounds__(256)
void proj_kernel(const float* __restrict__ A, const float* __restrict__ W,
                 const float* __restrict__ bias, float* __restrict__ out)
{
    __shared__ float Wt[64][NE + 4];   // transposed half of W, padded
    __shared__ float As[8][NE];

    const int t  = threadIdx.x;
    const int r0 = blockIdx.x * 8;

    for (int i = t; i < 8 * NE; i += 256) {
        As[i >> 7][i & 127] = A[(size_t)(r0 + (i >> 7)) * NE + (i & 127)];
    }

    const int c4 = (t & 31) * 4;
    const int rg = t >> 5;                     // row r0+rg
    float acc0 = 0, acc1 = 0, acc2 = 0, acc3 = 0;

    for (int eh = 0; eh < 2; ++eh) {
        if (eh) __syncthreads();               // previous half fully consumed
        for (int i = t; i < NE * 64; i += 256) {
            int c = i >> 6;
            int e = i & 63;
            Wt[e][c] = W[c * NE + eh * 64 + e];
        }
        __syncthreads();
#pragma unroll 8
        for (int e = 0; e < 64; ++e) {
            float4 wv = *(const float4*)&Wt[e][c4];
            float av = As[rg][eh * 64 + e];
            acc0 += av * wv.x; acc1 += av * wv.y;
            acc2 += av * wv.z; acc3 += av * wv.w;
        }
    }

    float4 bv = *(const float4*)&bias[c4];
    float4 o = make_float4(acc0 + bv.x, acc1 + bv.y, acc2 + bv.z, acc3 + bv.w);
    *(float4*)(out + (size_t)(r0 + rg) * NE + c4) = o;
}

extern "C" void kernel_launch(void* const* d_in, const int* in_sizes, int n_in,
                              void* d_out, int out_size, void* d_ws, size_t ws_size,
                              hipStream_t stream)
{
    (void)in_sizes; (void)n_in; (void)out_size; (void)d_ws; (void)ws_size;
    const float* x   = (const float*)d_in[0];
    const float* phi = (const float*)d_in[1];
    const float* W   = (const float*)d_in[2];
    const float* b   = (const float*)d_in[3];
    float* out = (float*)d_out;

    qattn_kernel<<<dim3(NB * NH * 8), dim3(512), 0, stream>>>(x, phi, out);
    proj_kernel<<<dim3(NB * NS / 8), dim3(256), 0, stream>>>(out, W, b, out);
}